// Round 1
// baseline (499.271 us; speedup 1.0000x reference)
//
#include <hip/hip_runtime.h>
#include <math.h>

#define B_ 8
#define C_ 128
#define N_ 16384
#define HID_ 128

// ws layout (float offsets)
#define WS_Z    0                 // 8*128            = 1024
#define WS_CTX  1024              // 8*4*32*32        = 32768
#define WS_BMAT 33792             // 8*128*128        = 131072
#define WS_A    164864            // 8*128*128        = 131072

// ---------------------------------------------------------------------------
// K1: per (b, 64-col n-tile): K,V = w_qkv[128:384] @ x_tile; ek = exp(K);
//     atomically accumulate Z[b][128] and ctx~[b][4][32][32].
// ---------------------------------------------------------------------------
__global__ __launch_bounds__(256) void k1_kv_ctx(const float* __restrict__ x,
                                                 const float* __restrict__ w_qkv,
                                                 float* __restrict__ ws) {
  __shared__ union {
    struct { float xs[128][64]; float ww[256][21]; } p1;   // 54.3 KB
    struct { float ek[128][68]; float vs[128][68]; } p2;   // 68 KB
  } sm;
  const int tid = threadIdx.x;
  const int b   = blockIdx.y;
  const int n0  = blockIdx.x * 64;
  const float* xb  = x + (size_t)b * C_ * N_;
  float* Z   = ws + WS_Z;
  float* ctx = ws + WS_CTX;

  // stage x tile [128 c][64 n]
  for (int k = 0; k < 8; ++k) {
    int idx = tid + k * 256;            // 2048 float4
    int row = idx >> 4, f4 = idx & 15;
    *(float4*)&sm.p1.xs[row][f4 * 4] =
        *(const float4*)(xb + (size_t)row * N_ + n0 + f4 * 4);
  }

  const int rg = tid >> 2;   // 0..63 -> rows rg*4..rg*4+3 (0..255)
  const int cg = tid & 3;    // cols cg*16..cg*16+15
  float acc[4][16];
  #pragma unroll
  for (int i = 0; i < 4; ++i)
    #pragma unroll
    for (int j = 0; j < 16; ++j) acc[i][j] = 0.f;

  for (int cc = 0; cc < 8; ++cc) {
    __syncthreads();
    // stage weight chunk: rows 0..255 = w_qkv rows 128..383, cols cc*16..+15
    for (int k = 0; k < 16; ++k) {
      int idx = tid + k * 256;          // 4096 scalars, coalesced
      int r = idx >> 4, c = idx & 15;
      sm.p1.ww[r][c] = w_qkv[(128 + r) * 128 + cc * 16 + c];
    }
    __syncthreads();
    #pragma unroll
    for (int c = 0; c < 16; ++c) {
      float w0 = sm.p1.ww[rg * 4 + 0][c];
      float w1 = sm.p1.ww[rg * 4 + 1][c];
      float w2 = sm.p1.ww[rg * 4 + 2][c];
      float w3 = sm.p1.ww[rg * 4 + 3][c];
      const float* xr = &sm.p1.xs[cc * 16 + c][cg * 16];
      #pragma unroll
      for (int j = 0; j < 16; ++j) {
        float xv = xr[j];
        acc[0][j] = fmaf(w0, xv, acc[0][j]);
        acc[1][j] = fmaf(w1, xv, acc[1][j]);
        acc[2][j] = fmaf(w2, xv, acc[2][j]);
        acc[3][j] = fmaf(w3, xv, acc[3][j]);
      }
    }
  }
  __syncthreads();

  // phase 2: rows<128 are K rows -> exp; rows>=128 are V rows. (uniform per thread)
  if (tid < 128) {
    #pragma unroll
    for (int i = 0; i < 4; ++i) {
      int r = rg * 4 + i;
      #pragma unroll
      for (int j = 0; j < 16; ++j) sm.p2.ek[r][cg * 16 + j] = __expf(acc[i][j]);
    }
  } else {
    #pragma unroll
    for (int i = 0; i < 4; ++i) {
      int r = rg * 4 + i - 128;
      #pragma unroll
      for (int j = 0; j < 16; ++j) sm.p2.vs[r][cg * 16 + j] = acc[i][j];
    }
  }
  __syncthreads();

  // Z partials: thread d sums its ek row over the 64 tile columns
  if (tid < 128) {
    float s = 0.f;
    #pragma unroll
    for (int n4 = 0; n4 < 16; ++n4) {
      float4 v = *(const float4*)&sm.p2.ek[tid][n4 * 4];
      s += v.x + v.y + v.z + v.w;
    }
    atomicAdd(&Z[b * 128 + tid], s);
  }

  // ctx~ partials: 4x4 (d,e) block per thread
  const int h = tid >> 6, dg = (tid >> 3) & 7, eg = tid & 7;
  float c44[4][4];
  #pragma unroll
  for (int i = 0; i < 4; ++i)
    #pragma unroll
    for (int j = 0; j < 4; ++j) c44[i][j] = 0.f;
  for (int n4 = 0; n4 < 16; ++n4) {
    float4 ekv[4], vv[4];
    #pragma unroll
    for (int i = 0; i < 4; ++i) ekv[i] = *(const float4*)&sm.p2.ek[h * 32 + dg * 4 + i][n4 * 4];
    #pragma unroll
    for (int j = 0; j < 4; ++j) vv[j]  = *(const float4*)&sm.p2.vs[h * 32 + eg * 4 + j][n4 * 4];
    #pragma unroll
    for (int i = 0; i < 4; ++i)
      #pragma unroll
      for (int j = 0; j < 4; ++j)
        c44[i][j] += ekv[i].x * vv[j].x + ekv[i].y * vv[j].y +
                     ekv[i].z * vv[j].z + ekv[i].w * vv[j].w;
  }
  #pragma unroll
  for (int i = 0; i < 4; ++i)
    #pragma unroll
    for (int j = 0; j < 4; ++j)
      atomicAdd(&ctx[((b * 4 + h) * 32 + dg * 4 + i) * 32 + eg * 4 + j], c44[i][j]);
}

// ---------------------------------------------------------------------------
// K2a: Bmat[b][h*32+e][c] = sum_d (ctx~[b][h][d][e]/Z[b][h*32+d]) * w_qkv[h*32+d][c]
// ---------------------------------------------------------------------------
__global__ __launch_bounds__(256) void k2a(const float* __restrict__ w_qkv,
                                           float* __restrict__ ws) {
  __shared__ float cn[32][33];
  __shared__ float wqs[32][128];
  const int tid = threadIdx.x;
  const int h = blockIdx.x, b = blockIdx.y;
  const float* Z   = ws + WS_Z + b * 128 + h * 32;
  const float* ctx = ws + WS_CTX + ((b * 4 + h) * 32) * 32;

  for (int k = 0; k < 4; ++k) {
    int idx = tid + k * 256;            // 1024
    int d = idx >> 5, e = idx & 31;
    cn[d][e] = ctx[d * 32 + e] / Z[d];
  }
  for (int k = 0; k < 4; ++k) {
    int idx = tid + k * 256;            // 1024 float4
    int d = idx >> 5, f4 = idx & 31;
    *(float4*)&wqs[d][f4 * 4] = *(const float4*)(w_qkv + (h * 32 + d) * 128 + f4 * 4);
  }
  __syncthreads();

  const int e = tid >> 3, cs = (tid & 7) * 16;
  float s[16];
  #pragma unroll
  for (int j = 0; j < 16; ++j) s[j] = 0.f;
  for (int d = 0; d < 32; ++d) {
    float v = cn[d][e];
    #pragma unroll
    for (int j = 0; j < 16; ++j) s[j] = fmaf(v, wqs[d][cs + j], s[j]);
  }
  float* Bm = ws + WS_BMAT + ((size_t)b * 128 + h * 32 + e) * 128;
  #pragma unroll
  for (int j = 0; j < 16; ++j) Bm[cs + j] = s[j];
}

// ---------------------------------------------------------------------------
// K2b: A[b] = w_out @ Bmat[b]   (each block: 32 rows of A)
// ---------------------------------------------------------------------------
__global__ __launch_bounds__(256) void k2b(const float* __restrict__ w_out,
                                           float* __restrict__ ws) {
  __shared__ float bs[128][128];
  __shared__ float wos[32][128];
  const int tid = threadIdx.x;
  const int oq = blockIdx.x, b = blockIdx.y;
  const float* Bm = ws + WS_BMAT + (size_t)b * 128 * 128;

  for (int k = 0; k < 16; ++k) {
    int idx = tid + k * 256;            // 4096 float4
    int r = idx >> 5, f4 = idx & 31;
    *(float4*)&bs[r][f4 * 4] = *(const float4*)(Bm + r * 128 + f4 * 4);
  }
  for (int k = 0; k < 4; ++k) {
    int idx = tid + k * 256;            // 1024 float4
    int r = idx >> 5, f4 = idx & 31;
    *(float4*)&wos[r][f4 * 4] = *(const float4*)(w_out + (oq * 32 + r) * 128 + f4 * 4);
  }
  __syncthreads();

  const int ol = tid >> 3, cq = (tid & 7) * 16;
  float s[16];
  #pragma unroll
  for (int j = 0; j < 16; ++j) s[j] = 0.f;
  for (int eg = 0; eg < 128; ++eg) {
    float w = wos[ol][eg];
    #pragma unroll
    for (int j = 0; j < 16; ++j) s[j] = fmaf(w, bs[eg][cq + j], s[j]);
  }
  float* A = ws + WS_A + ((size_t)b * 128 + oq * 32 + ol) * 128;
  #pragma unroll
  for (int j = 0; j < 16; ++j) A[cq + j] = s[j];
}

// ---------------------------------------------------------------------------
// K3: y[b] = A[b] @ x[b] + b_out
// ---------------------------------------------------------------------------
__global__ __launch_bounds__(256) void k3(const float* __restrict__ x,
                                          const float* __restrict__ b_out,
                                          const float* __restrict__ ws,
                                          float* __restrict__ y) {
  __shared__ float xs[128][128];        // 64 KB
  __shared__ float as[128][21];         // 10.5 KB
  const int tid = threadIdx.x;
  const int b  = blockIdx.y;
  const int n0 = blockIdx.x * 128;
  const float* xb = x + (size_t)b * C_ * N_;
  const float* A  = ws + WS_A + (size_t)b * 128 * 128;

  for (int k = 0; k < 16; ++k) {
    int idx = tid + k * 256;            // 4096 float4
    int row = idx >> 5, f4 = idx & 31;
    *(float4*)&xs[row][f4 * 4] =
        *(const float4*)(xb + (size_t)row * N_ + n0 + f4 * 4);
  }

  const int rg = tid >> 3;   // 0..31 -> rows rg*4..+3
  const int cg = tid & 7;    // cols cg*16..+15
  float acc[4][16];
  #pragma unroll
  for (int i = 0; i < 4; ++i)
    #pragma unroll
    for (int j = 0; j < 16; ++j) acc[i][j] = 0.f;

  for (int cc = 0; cc < 8; ++cc) {
    __syncthreads();
    for (int k = 0; k < 8; ++k) {
      int idx = tid + k * 256;          // 2048 scalars
      int r = idx >> 4, c = idx & 15;
      as[r][c] = A[r * 128 + cc * 16 + c];
    }
    __syncthreads();
    #pragma unroll
    for (int c = 0; c < 16; ++c) {
      float w0 = as[rg * 4 + 0][c];
      float w1 = as[rg * 4 + 1][c];
      float w2 = as[rg * 4 + 2][c];
      float w3 = as[rg * 4 + 3][c];
      const float* xr = &xs[cc * 16 + c][cg * 16];
      #pragma unroll
      for (int j = 0; j < 16; ++j) {
        float xv = xr[j];
        acc[0][j] = fmaf(w0, xv, acc[0][j]);
        acc[1][j] = fmaf(w1, xv, acc[1][j]);
        acc[2][j] = fmaf(w2, xv, acc[2][j]);
        acc[3][j] = fmaf(w3, xv, acc[3][j]);
      }
    }
  }

  float* yb = y + (size_t)b * HID_ * N_;
  #pragma unroll
  for (int i = 0; i < 4; ++i) {
    int row = rg * 4 + i;
    float bias = b_out[row];
    #pragma unroll
    for (int j4 = 0; j4 < 4; ++j4) {
      float4 v;
      v.x = acc[i][j4 * 4 + 0] + bias;
      v.y = acc[i][j4 * 4 + 1] + bias;
      v.z = acc[i][j4 * 4 + 2] + bias;
      v.w = acc[i][j4 * 4 + 3] + bias;
      *(float4*)(yb + (size_t)row * N_ + n0 + cg * 16 + j4 * 4) = v;
    }
  }
}

extern "C" void kernel_launch(void* const* d_in, const int* in_sizes, int n_in,
                              void* d_out, int out_size, void* d_ws, size_t ws_size,
                              hipStream_t stream) {
  const float* x     = (const float*)d_in[0];
  const float* w_qkv = (const float*)d_in[1];
  const float* w_out = (const float*)d_in[2];
  const float* b_out = (const float*)d_in[3];
  float* y  = (float*)d_out;
  float* ws = (float*)d_ws;

  // zero atomic accumulators (Z + ctx) — must happen every call
  hipMemsetAsync(ws, 0, (1024 + 32768) * sizeof(float), stream);

  k1_kv_ctx<<<dim3(256, 8), 256, 0, stream>>>(x, w_qkv, ws);
  k2a<<<dim3(4, 8), 256, 0, stream>>>(w_qkv, ws);
  k2b<<<dim3(4, 8), 256, 0, stream>>>(w_out, ws);
  k3<<<dim3(128, 8), 256, 0, stream>>>(x, b_out, ws, y);
}

// Round 2
// 103.504 us; speedup vs baseline: 4.8237x; 4.8237x over previous
//
#include <hip/hip_runtime.h>
#include <math.h>

#define B_ 8
#define C_ 128
#define N_ 16384

// ws layout (float offsets)
#define WS_Z    0                 // 8*128            = 1024
#define WS_CTX  1024              // 8*4*32*32        = 32768
#define WS_BMAT 33792             // 8*128*128        = 131072
#define WS_A    164864            // 8*128*128        = 131072

typedef __attribute__((ext_vector_type(8))) short bf16x8;
typedef __attribute__((ext_vector_type(4))) float f32x4;

__device__ __forceinline__ unsigned short f2bf(float f) {
  unsigned int u = __float_as_uint(f);
  u += 0x7fffu + ((u >> 16) & 1u);          // RNE
  return (unsigned short)(u >> 16);
}

__device__ __forceinline__ bf16x8 lds_frag(const unsigned short* p) {
  bf16x8 f;
  ((unsigned long long*)&f)[0] = ((const unsigned long long*)p)[0];
  ((unsigned long long*)&f)[1] = ((const unsigned long long*)p)[1];
  return f;
}

// ---------------------------------------------------------------------------
// K1: per (b, 256-n chunk): KV = Wkv @ x (bf16 MFMA, fp32 accum);
//     ek = exp(K); ctx[h] += ek_h @ v_h^T (MFMA); Z += rowsum(ek).
// Wave w owns KV rows 64w..64w+63 (waves 0,1 = K rows; 2,3 = V rows).
// ---------------------------------------------------------------------------
__global__ __launch_bounds__(256) void k1_kv_ctx(const float* __restrict__ x,
                                                 const float* __restrict__ wqkv,
                                                 float* __restrict__ ws) {
  // xs: x subtile, [n=64][c=128] bf16, row stride 132 u16 = 264 B
  //   -> frag reads (16 rows, same col block) hit banks (2n)%32: conflict-free.
  __shared__ __align__(16) unsigned short xs[64][132];      // 16.9 KB
  // ekv[0]=ek rows 0..127, ekv[1]=v rows 0..127; [row][n=64], stride 68 u16.
  __shared__ __align__(16) unsigned short ekv[2][128][68];  // 34.8 KB
  const int tid  = threadIdx.x;
  const int wave = tid >> 6;
  const int l15  = tid & 15;
  const int l4   = (tid >> 4) & 3;
  const int b    = blockIdx.y;
  const int nchunk0 = blockIdx.x * 256;
  const float* xb = x + (size_t)b * ((size_t)C_ * N_);
  const int wrow0 = wave * 64;

  // A-fragments of W (bf16) in registers, loaded once per block (L2-hot).
  // A[m][k] layout: elem j of lane l = W[m0 + (l&15)][k0 + (l>>4)*8 + j]
  bf16x8 wf[4][4];
  #pragma unroll
  for (int mi = 0; mi < 4; ++mi) {
    #pragma unroll
    for (int ki = 0; ki < 4; ++ki) {
      const float* p = wqkv + (size_t)(128 + wrow0 + mi * 16 + l15) * C_ + ki * 32 + l4 * 8;
      float4 u = *(const float4*)p;
      float4 v = *(const float4*)(p + 4);
      bf16x8 f;
      f[0] = (short)f2bf(u.x); f[1] = (short)f2bf(u.y);
      f[2] = (short)f2bf(u.z); f[3] = (short)f2bf(u.w);
      f[4] = (short)f2bf(v.x); f[5] = (short)f2bf(v.y);
      f[6] = (short)f2bf(v.z); f[7] = (short)f2bf(v.w);
      wf[mi][ki] = f;
    }
  }

  const f32x4 z4 = {0.f, 0.f, 0.f, 0.f};
  f32x4 ctxacc[2][2];
  #pragma unroll
  for (int i = 0; i < 2; ++i)
    #pragma unroll
    for (int j = 0; j < 2; ++j) ctxacc[i][j] = z4;
  float zacc[4][4];
  #pragma unroll
  for (int i = 0; i < 4; ++i)
    #pragma unroll
    for (int j = 0; j < 4; ++j) zacc[i][j] = 0.f;

  for (int st = 0; st < 4; ++st) {
    const int nb = nchunk0 + st * 64;
    __syncthreads();   // prior xs reads + prior ekv reads complete
    // stage x subtile: coalesced float4 loads over n, bf16 u16 scatter to [n][c]
    #pragma unroll
    for (int i = 0; i < 8; ++i) {
      int idx = tid + i * 256;            // 2048 float4
      int k = idx >> 4, n4 = idx & 15;
      float4 v = *(const float4*)(xb + (size_t)k * N_ + nb + n4 * 4);
      xs[n4 * 4 + 0][k] = f2bf(v.x);
      xs[n4 * 4 + 1][k] = f2bf(v.y);
      xs[n4 * 4 + 2][k] = f2bf(v.z);
      xs[n4 * 4 + 3][k] = f2bf(v.w);
    }
    __syncthreads();

    // KV = W @ x : 4 m-tiles x 4 n-tiles x 4 k-steps of 16x16x32
    f32x4 acc[4][4];
    #pragma unroll
    for (int mi = 0; mi < 4; ++mi)
      #pragma unroll
      for (int ni = 0; ni < 4; ++ni) acc[mi][ni] = z4;
    #pragma unroll
    for (int ki = 0; ki < 4; ++ki) {
      bf16x8 bfr[4];
      #pragma unroll
      for (int ni = 0; ni < 4; ++ni)
        bfr[ni] = lds_frag(&xs[ni * 16 + l15][ki * 32 + l4 * 8]);
      #pragma unroll
      for (int mi = 0; mi < 4; ++mi)
        #pragma unroll
        for (int ni = 0; ni < 4; ++ni)
          acc[mi][ni] = __builtin_amdgcn_mfma_f32_16x16x32_bf16(
              wf[mi][ki], bfr[ni], acc[mi][ni], 0, 0, 0);
    }

    // phase 2: exp for K-waves (+Z partials), convert, restage as bf16.
    // C layout: row = mi*16 + l4*4 + r, col = ni*16 + l15.
    if (wave < 2) {
      #pragma unroll
      for (int mi = 0; mi < 4; ++mi) {
        int row = wrow0 + mi * 16 + l4 * 4;
        #pragma unroll
        for (int ni = 0; ni < 4; ++ni)
          #pragma unroll
          for (int r = 0; r < 4; ++r) {
            float e = __expf(acc[mi][ni][r]);
            zacc[mi][r] += e;
            ekv[0][row + r][ni * 16 + l15] = f2bf(e);
          }
      }
    } else {
      #pragma unroll
      for (int mi = 0; mi < 4; ++mi) {
        int row = wrow0 - 128 + mi * 16 + l4 * 4;
        #pragma unroll
        for (int ni = 0; ni < 4; ++ni)
          #pragma unroll
          for (int r = 0; r < 4; ++r)
            ekv[1][row + r][ni * 16 + l15] = f2bf(acc[mi][ni][r]);
      }
    }
    __syncthreads();

    // ctx_h[d][e] += sum_n ek[32h+d][n] * v[32h+e][n]; wave = head
    #pragma unroll
    for (int ki = 0; ki < 2; ++ki) {
      bf16x8 af[2], bf2[2];
      #pragma unroll
      for (int mi2 = 0; mi2 < 2; ++mi2)
        af[mi2] = lds_frag(&ekv[0][wave * 32 + mi2 * 16 + l15][ki * 32 + l4 * 8]);
      #pragma unroll
      for (int ni2 = 0; ni2 < 2; ++ni2)
        bf2[ni2] = lds_frag(&ekv[1][wave * 32 + ni2 * 16 + l15][ki * 32 + l4 * 8]);
      #pragma unroll
      for (int mi2 = 0; mi2 < 2; ++mi2)
        #pragma unroll
        for (int ni2 = 0; ni2 < 2; ++ni2)
          ctxacc[mi2][ni2] = __builtin_amdgcn_mfma_f32_16x16x32_bf16(
              af[mi2], bf2[ni2], ctxacc[mi2][ni2], 0, 0, 0);
    }
  }

  // epilogue: one atomic per ctx element per block; Z via shfl reduce
  float* ctx = ws + WS_CTX + (size_t)((b * 4 + wave) * 32) * 32;
  #pragma unroll
  for (int mi2 = 0; mi2 < 2; ++mi2)
    #pragma unroll
    for (int ni2 = 0; ni2 < 2; ++ni2)
      #pragma unroll
      for (int r = 0; r < 4; ++r)
        atomicAdd(&ctx[(mi2 * 16 + l4 * 4 + r) * 32 + ni2 * 16 + l15],
                  ctxacc[mi2][ni2][r]);

  if (wave < 2) {
    #pragma unroll
    for (int mi = 0; mi < 4; ++mi)
      #pragma unroll
      for (int r = 0; r < 4; ++r) {
        float z = zacc[mi][r];
        z += __shfl_xor(z, 1);
        z += __shfl_xor(z, 2);
        z += __shfl_xor(z, 4);
        z += __shfl_xor(z, 8);
        if (l15 == 0)
          atomicAdd(&ws[WS_Z + b * 128 + wrow0 + mi * 16 + l4 * 4 + r], z);
      }
  }
}

// ---------------------------------------------------------------------------
// K2a: Bmat[b][h*32+e][c] = sum_d (ctx~[b][h][d][e]/Z[b][h*32+d]) * w_qkv[h*32+d][c]
// ---------------------------------------------------------------------------
__global__ __launch_bounds__(256) void k2a(const float* __restrict__ w_qkv,
                                           float* __restrict__ ws) {
  __shared__ float cn[32][33];
  __shared__ float wqs[32][128];
  const int tid = threadIdx.x;
  const int h = blockIdx.x, b = blockIdx.y;
  const float* Z   = ws + WS_Z + b * 128 + h * 32;
  const float* ctx = ws + WS_CTX + ((b * 4 + h) * 32) * 32;

  for (int k = 0; k < 4; ++k) {
    int idx = tid + k * 256;
    int d = idx >> 5, e = idx & 31;
    cn[d][e] = ctx[d * 32 + e] / Z[d];
  }
  for (int k = 0; k < 4; ++k) {
    int idx = tid + k * 256;
    int d = idx >> 5, f4 = idx & 31;
    *(float4*)&wqs[d][f4 * 4] = *(const float4*)(w_qkv + (h * 32 + d) * 128 + f4 * 4);
  }
  __syncthreads();

  const int e = tid >> 3, cs = (tid & 7) * 16;
  float s[16];
  #pragma unroll
  for (int j = 0; j < 16; ++j) s[j] = 0.f;
  for (int d = 0; d < 32; ++d) {
    float v = cn[d][e];
    #pragma unroll
    for (int j = 0; j < 16; ++j) s[j] = fmaf(v, wqs[d][cs + j], s[j]);
  }
  float* Bm = ws + WS_BMAT + ((size_t)b * 128 + h * 32 + e) * 128;
  #pragma unroll
  for (int j = 0; j < 16; ++j) Bm[cs + j] = s[j];
}

// ---------------------------------------------------------------------------
// K2b: A[b] = w_out @ Bmat[b]
// ---------------------------------------------------------------------------
__global__ __launch_bounds__(256) void k2b(const float* __restrict__ w_out,
                                           float* __restrict__ ws) {
  __shared__ float bs[128][128];
  __shared__ float wos[32][128];
  const int tid = threadIdx.x;
  const int oq = blockIdx.x, b = blockIdx.y;
  const float* Bm = ws + WS_BMAT + (size_t)b * 128 * 128;

  for (int k = 0; k < 16; ++k) {
    int idx = tid + k * 256;
    int r = idx >> 5, f4 = idx & 31;
    *(float4*)&bs[r][f4 * 4] = *(const float4*)(Bm + r * 128 + f4 * 4);
  }
  for (int k = 0; k < 4; ++k) {
    int idx = tid + k * 256;
    int r = idx >> 5, f4 = idx & 31;
    *(float4*)&wos[r][f4 * 4] = *(const float4*)(w_out + (oq * 32 + r) * 128 + f4 * 4);
  }
  __syncthreads();

  const int ol = tid >> 3, cq = (tid & 7) * 16;
  float s[16];
  #pragma unroll
  for (int j = 0; j < 16; ++j) s[j] = 0.f;
  for (int eg = 0; eg < 128; ++eg) {
    float w = wos[ol][eg];
    #pragma unroll
    for (int j = 0; j < 16; ++j) s[j] = fmaf(w, bs[eg][cq + j], s[j]);
  }
  float* A = ws + WS_A + ((size_t)b * 128 + oq * 32 + ol) * 128;
  #pragma unroll
  for (int j = 0; j < 16; ++j) A[cq + j] = s[j];
}

// ---------------------------------------------------------------------------
// K3: y[b] = A[b] @ x[b] + b_out  (bf16 MFMA, fp32 accum/store)
// Wave w owns y rows 32w..32w+31.
// ---------------------------------------------------------------------------
__global__ __launch_bounds__(256) void k3(const float* __restrict__ x,
                                          const float* __restrict__ bout,
                                          const float* __restrict__ ws,
                                          float* __restrict__ y) {
  __shared__ __align__(16) unsigned short xs[64][132];
  const int tid  = threadIdx.x;
  const int wave = tid >> 6;
  const int l15  = tid & 15;
  const int l4   = (tid >> 4) & 3;
  const int b    = blockIdx.y;
  const int nchunk0 = blockIdx.x * 128;
  const float* xb = x + (size_t)b * ((size_t)C_ * N_);
  const float* A  = ws + WS_A + (size_t)b * 128 * 128;

  bf16x8 af[2][4];
  #pragma unroll
  for (int mi = 0; mi < 2; ++mi) {
    #pragma unroll
    for (int ki = 0; ki < 4; ++ki) {
      const float* p = A + (size_t)(wave * 32 + mi * 16 + l15) * 128 + ki * 32 + l4 * 8;
      float4 u = *(const float4*)p;
      float4 v = *(const float4*)(p + 4);
      bf16x8 f;
      f[0] = (short)f2bf(u.x); f[1] = (short)f2bf(u.y);
      f[2] = (short)f2bf(u.z); f[3] = (short)f2bf(u.w);
      f[4] = (short)f2bf(v.x); f[5] = (short)f2bf(v.y);
      f[6] = (short)f2bf(v.z); f[7] = (short)f2bf(v.w);
      af[mi][ki] = f;
    }
  }
  float bias[2][4];
  #pragma unroll
  for (int mi = 0; mi < 2; ++mi)
    #pragma unroll
    for (int r = 0; r < 4; ++r)
      bias[mi][r] = bout[wave * 32 + mi * 16 + l4 * 4 + r];

  const f32x4 z4 = {0.f, 0.f, 0.f, 0.f};
  float* yb = y + (size_t)b * ((size_t)128 * N_);

  for (int st = 0; st < 2; ++st) {
    const int nb = nchunk0 + st * 64;
    __syncthreads();
    #pragma unroll
    for (int i = 0; i < 8; ++i) {
      int idx = tid + i * 256;
      int k = idx >> 4, n4 = idx & 15;
      float4 v = *(const float4*)(xb + (size_t)k * N_ + nb + n4 * 4);
      xs[n4 * 4 + 0][k] = f2bf(v.x);
      xs[n4 * 4 + 1][k] = f2bf(v.y);
      xs[n4 * 4 + 2][k] = f2bf(v.z);
      xs[n4 * 4 + 3][k] = f2bf(v.w);
    }
    __syncthreads();

    f32x4 acc[2][4];
    #pragma unroll
    for (int mi = 0; mi < 2; ++mi)
      #pragma unroll
      for (int ni = 0; ni < 4; ++ni) acc[mi][ni] = z4;
    #pragma unroll
    for (int ki = 0; ki < 4; ++ki) {
      bf16x8 bfr[4];
      #pragma unroll
      for (int ni = 0; ni < 4; ++ni)
        bfr[ni] = lds_frag(&xs[ni * 16 + l15][ki * 32 + l4 * 8]);
      #pragma unroll
      for (int mi = 0; mi < 2; ++mi)
        #pragma unroll
        for (int ni = 0; ni < 4; ++ni)
          acc[mi][ni] = __builtin_amdgcn_mfma_f32_16x16x32_bf16(
              af[mi][ki], bfr[ni], acc[mi][ni], 0, 0, 0);
    }

    #pragma unroll
    for (int mi = 0; mi < 2; ++mi)
      #pragma unroll
      for (int ni = 0; ni < 4; ++ni)
        #pragma unroll
        for (int r = 0; r < 4; ++r)
          yb[(size_t)(wave * 32 + mi * 16 + l4 * 4 + r) * N_ + nb + ni * 16 + l15] =
              acc[mi][ni][r] + bias[mi][r];
  }
}

extern "C" void kernel_launch(void* const* d_in, const int* in_sizes, int n_in,
                              void* d_out, int out_size, void* d_ws, size_t ws_size,
                              hipStream_t stream) {
  const float* x     = (const float*)d_in[0];
  const float* w_qkv = (const float*)d_in[1];
  const float* w_out = (const float*)d_in[2];
  const float* b_out = (const float*)d_in[3];
  float* y  = (float*)d_out;
  float* ws = (float*)d_ws;

  hipMemsetAsync(ws, 0, (1024 + 32768) * sizeof(float), stream);

  k1_kv_ctx<<<dim3(64, 8), 256, 0, stream>>>(x, w_qkv, ws);
  k2a<<<dim3(4, 8), 256, 0, stream>>>(w_qkv, ws);
  k2b<<<dim3(4, 8), 256, 0, stream>>>(w_out, ws);
  k3<<<dim3(128, 8), 256, 0, stream>>>(x, b_out, ws, y);
}

// Round 3
// 89.295 us; speedup vs baseline: 5.5913x; 1.1591x over previous
//
#include <hip/hip_runtime.h>
#include <math.h>

#define C_ 128
#define N_ 16384

// ws layout (float offsets)
#define WS_Z    0                          // 8*128
#define WS_CTX  1024                       // 8*4*32*32
#define WS_BMAT 33792                      // 8*128*128
#define WS_A    164864                     // 8*128*128
#define WS_PCTX 295936                     // 1024 slots * 4096
#define WS_PZ   (WS_PCTX + 1024*4096)      // 512 blocks * 128
#define WS_END  (WS_PZ + 512*128)

typedef __attribute__((ext_vector_type(8))) short bf16x8;
typedef __attribute__((ext_vector_type(4))) float f32x4;
typedef __attribute__((ext_vector_type(4))) unsigned int u32x4;

__device__ __forceinline__ unsigned int pkbf(float a, float b) {
  unsigned int r;
  asm("v_cvt_pk_bf16_f32 %0, %1, %2" : "=v"(r) : "v"(a), "v"(b));
  return r;
}

__device__ __forceinline__ bf16x8 make_frag(float4 u, float4 v) {
  u32x4 q = {pkbf(u.x, u.y), pkbf(u.z, u.w), pkbf(v.x, v.y), pkbf(v.z, v.w)};
  return *(bf16x8*)&q;
}

__device__ __forceinline__ bf16x8 lds_frag(const unsigned short* p) {
  bf16x8 f;
  ((unsigned long long*)&f)[0] = ((const unsigned long long*)p)[0];
  ((unsigned long long*)&f)[1] = ((const unsigned long long*)p)[1];
  return f;
}

// ---------------------------------------------------------------------------
// K1: per (b, 256-n chunk), 512 thr / 8 waves. Wave (h = w&3, t = w>>2):
//   t=0 -> K rows h*32..h*32+31, t=1 -> V rows. KV = Wkv @ x via MFMA;
//   ek = exp(K); ctx_h[d][e] += ek_h @ v_h^T (k-half t per wave).
//   Output: block-private partial slot (no atomics) or atomic fallback.
// ---------------------------------------------------------------------------
template<bool ATOMIC>
__global__ __launch_bounds__(512, 4) void k1_kv_ctx(const float* __restrict__ x,
                                                    const float* __restrict__ wqkv,
                                                    float* __restrict__ ws) {
  // union: xs[64][132] u16 (first 8448) | ekv[2][128][68] u16 (17408 total)
  __shared__ __attribute__((aligned(16))) unsigned short smem[2 * 128 * 68];
#define XS(n, c)    smem[(n) * 132 + (c)]
#define EKV(t, r, c) smem[((t) * 128 + (r)) * 68 + (c)]
  const int tid  = threadIdx.x;
  const int wave = tid >> 6;
  const int l15  = tid & 15;
  const int l4   = (tid >> 4) & 3;
  const int b    = blockIdx.y;
  const int j    = blockIdx.x;          // n-chunk 0..63
  const int h    = wave & 3;            // head / 32-row group
  const int t    = wave >> 2;           // 0 = K half, 1 = V half
  const int kvrow0 = h * 32 + t * 128;  // row within the 256 KV rows
  const float* xb = x + (size_t)b * ((size_t)C_ * N_);

  // W fragments pinned in registers (32 VGPR)
  bf16x8 wf[2][4];
  #pragma unroll
  for (int mi = 0; mi < 2; ++mi)
    #pragma unroll
    for (int ki = 0; ki < 4; ++ki) {
      const float* p = wqkv + (size_t)(128 + kvrow0 + mi * 16 + l15) * C_ + ki * 32 + l4 * 8;
      wf[mi][ki] = make_frag(*(const float4*)p, *(const float4*)(p + 4));
    }

  const f32x4 z4 = {0.f, 0.f, 0.f, 0.f};
  f32x4 ctxacc[2][2];
  #pragma unroll
  for (int i = 0; i < 2; ++i)
    #pragma unroll
    for (int jj = 0; jj < 2; ++jj) ctxacc[i][jj] = z4;
  float zacc[2][4];
  #pragma unroll
  for (int i = 0; i < 2; ++i)
    #pragma unroll
    for (int r = 0; r < 4; ++r) zacc[i][r] = 0.f;

  for (int st = 0; st < 4; ++st) {
    const int nb = j * 256 + st * 64;
    __syncthreads();                    // prev ctx-MFMA ekv reads done
    // stage x subtile [n=64][c=128] bf16 (transposed scatter)
    #pragma unroll
    for (int i = 0; i < 4; ++i) {
      int idx = tid + i * 512;          // 2048 float4
      int k = idx >> 4, n4 = idx & 15;
      float4 v = *(const float4*)(xb + (size_t)k * N_ + nb + n4 * 4);
      unsigned int p01 = pkbf(v.x, v.y), p23 = pkbf(v.z, v.w);
      XS(n4 * 4 + 0, k) = (unsigned short)p01;
      XS(n4 * 4 + 1, k) = (unsigned short)(p01 >> 16);
      XS(n4 * 4 + 2, k) = (unsigned short)p23;
      XS(n4 * 4 + 3, k) = (unsigned short)(p23 >> 16);
    }
    __syncthreads();

    // KV = W @ x : 2 mi x 4 ni x 4 ki
    f32x4 acc[2][4];
    #pragma unroll
    for (int mi = 0; mi < 2; ++mi)
      #pragma unroll
      for (int ni = 0; ni < 4; ++ni) acc[mi][ni] = z4;
    #pragma unroll
    for (int ki = 0; ki < 4; ++ki) {
      bf16x8 bfr[4];
      #pragma unroll
      for (int ni = 0; ni < 4; ++ni)
        bfr[ni] = lds_frag(&XS(ni * 16 + l15, ki * 32 + l4 * 8));
      #pragma unroll
      for (int mi = 0; mi < 2; ++mi)
        #pragma unroll
        for (int ni = 0; ni < 4; ++ni)
          acc[mi][ni] = __builtin_amdgcn_mfma_f32_16x16x32_bf16(
              wf[mi][ki], bfr[ni], acc[mi][ni], 0, 0, 0);
    }
    __syncthreads();                    // xs reads done; ekv region writable

    // exp (K waves) / passthrough (V waves), restage bf16 into EKV
    #pragma unroll
    for (int mi = 0; mi < 2; ++mi) {
      int rb = h * 32 + mi * 16 + l4 * 4;
      #pragma unroll
      for (int ni = 0; ni < 4; ++ni) {
        int col = ni * 16 + l15;
        float e0, e1, e2, e3;
        if (t == 0) {
          e0 = __expf(acc[mi][ni][0]); e1 = __expf(acc[mi][ni][1]);
          e2 = __expf(acc[mi][ni][2]); e3 = __expf(acc[mi][ni][3]);
          zacc[mi][0] += e0; zacc[mi][1] += e1;
          zacc[mi][2] += e2; zacc[mi][3] += e3;
        } else {
          e0 = acc[mi][ni][0]; e1 = acc[mi][ni][1];
          e2 = acc[mi][ni][2]; e3 = acc[mi][ni][3];
        }
        unsigned int p01 = pkbf(e0, e1), p23 = pkbf(e2, e3);
        EKV(t, rb + 0, col) = (unsigned short)p01;
        EKV(t, rb + 1, col) = (unsigned short)(p01 >> 16);
        EKV(t, rb + 2, col) = (unsigned short)p23;
        EKV(t, rb + 3, col) = (unsigned short)(p23 >> 16);
      }
    }
    __syncthreads();                    // ekv ready

    // ctx_h[d][e] += sum over n-half t
    {
      bf16x8 af[2], bfv[2];
      #pragma unroll
      for (int m2 = 0; m2 < 2; ++m2)
        af[m2] = lds_frag(&EKV(0, h * 32 + m2 * 16 + l15, t * 32 + l4 * 8));
      #pragma unroll
      for (int n2 = 0; n2 < 2; ++n2)
        bfv[n2] = lds_frag(&EKV(1, h * 32 + n2 * 16 + l15, t * 32 + l4 * 8));
      #pragma unroll
      for (int m2 = 0; m2 < 2; ++m2)
        #pragma unroll
        for (int n2 = 0; n2 < 2; ++n2)
          ctxacc[m2][n2] = __builtin_amdgcn_mfma_f32_16x16x32_bf16(
              af[m2], bfv[n2], ctxacc[m2][n2], 0, 0, 0);
    }
  }

  // epilogue
  if (!ATOMIC) {
    float* ps = ws + WS_PCTX + (size_t)((b * 64 + j) * 2 + t) * 4096 + h * 1024;
    #pragma unroll
    for (int m2 = 0; m2 < 2; ++m2)
      #pragma unroll
      for (int n2 = 0; n2 < 2; ++n2)
        #pragma unroll
        for (int r = 0; r < 4; ++r)
          ps[(m2 * 16 + l4 * 4 + r) * 32 + n2 * 16 + l15] = ctxacc[m2][n2][r];
  } else {
    float* ctx = ws + WS_CTX + (size_t)(b * 4 + h) * 1024;
    #pragma unroll
    for (int m2 = 0; m2 < 2; ++m2)
      #pragma unroll
      for (int n2 = 0; n2 < 2; ++n2)
        #pragma unroll
        for (int r = 0; r < 4; ++r)
          atomicAdd(&ctx[(m2 * 16 + l4 * 4 + r) * 32 + n2 * 16 + l15],
                    ctxacc[m2][n2][r]);
  }
  if (t == 0) {
    #pragma unroll
    for (int mi = 0; mi < 2; ++mi)
      #pragma unroll
      for (int r = 0; r < 4; ++r) {
        float z = zacc[mi][r];
        z += __shfl_xor(z, 1);
        z += __shfl_xor(z, 2);
        z += __shfl_xor(z, 4);
        z += __shfl_xor(z, 8);
        if (l15 == 0) {
          int row = h * 32 + mi * 16 + l4 * 4 + r;
          if (!ATOMIC)
            ws[WS_PZ + (size_t)(b * 64 + j) * 128 + row] = z;
          else
            atomicAdd(&ws[WS_Z + b * 128 + row], z);
        }
      }
  }
#undef XS
#undef EKV
}

// ---------------------------------------------------------------------------
// K1b: reduce partials -> WS_CTX, WS_Z
// ---------------------------------------------------------------------------
__global__ __launch_bounds__(256) void k1b(float* __restrict__ ws) {
  const int tid = threadIdx.x;
  const int eq = blockIdx.x;   // 0..3
  const int h  = blockIdx.y;   // 0..3
  const int b  = blockIdx.z;   // 0..7
  const int el = eq * 256 + tid;
  const float* p = ws + WS_PCTX + (size_t)(b * 128) * 4096 + h * 1024 + el;
  float s = 0.f;
  #pragma unroll 8
  for (int jj = 0; jj < 128; ++jj) s += p[(size_t)jj * 4096];
  ws[WS_CTX + (size_t)(b * 4 + h) * 1024 + el] = s;
  if (eq == 0 && tid < 32) {
    const float* pz = ws + WS_PZ + (size_t)(b * 64) * 128 + h * 32 + tid;
    float z = 0.f;
    #pragma unroll 8
    for (int jj = 0; jj < 64; ++jj) z += pz[(size_t)jj * 128];
    ws[WS_Z + b * 128 + h * 32 + tid] = z;
  }
}

// ---------------------------------------------------------------------------
// K2a: Bmat[b][h*32+e][c] = sum_d (ctx[b][h][d][e]/Z[b][h*32+d]) * w_qkv[h*32+d][c]
// ---------------------------------------------------------------------------
__global__ __launch_bounds__(256) void k2a(const float* __restrict__ w_qkv,
                                           float* __restrict__ ws) {
  __shared__ float cn[32][33];
  __shared__ float wqs[32][128];
  const int tid = threadIdx.x;
  const int h = blockIdx.x, b = blockIdx.y;
  const float* Z   = ws + WS_Z + b * 128 + h * 32;
  const float* ctx = ws + WS_CTX + ((b * 4 + h) * 32) * 32;

  for (int k = 0; k < 4; ++k) {
    int idx = tid + k * 256;
    int d = idx >> 5, e = idx & 31;
    cn[d][e] = ctx[d * 32 + e] / Z[d];
  }
  for (int k = 0; k < 4; ++k) {
    int idx = tid + k * 256;
    int d = idx >> 5, f4 = idx & 31;
    *(float4*)&wqs[d][f4 * 4] = *(const float4*)(w_qkv + (h * 32 + d) * 128 + f4 * 4);
  }
  __syncthreads();

  const int e = tid >> 3, cs = (tid & 7) * 16;
  float s[16];
  #pragma unroll
  for (int jj = 0; jj < 16; ++jj) s[jj] = 0.f;
  for (int d = 0; d < 32; ++d) {
    float v = cn[d][e];
    #pragma unroll
    for (int jj = 0; jj < 16; ++jj) s[jj] = fmaf(v, wqs[d][cs + jj], s[jj]);
  }
  float* Bm = ws + WS_BMAT + ((size_t)b * 128 + h * 32 + e) * 128;
  #pragma unroll
  for (int jj = 0; jj < 16; ++jj) Bm[cs + jj] = s[jj];
}

// ---------------------------------------------------------------------------
// K2b: A[b] = w_out @ Bmat[b]
// ---------------------------------------------------------------------------
__global__ __launch_bounds__(256) void k2b(const float* __restrict__ w_out,
                                           float* __restrict__ ws) {
  __shared__ float bs[128][128];
  __shared__ float wos[32][128];
  const int tid = threadIdx.x;
  const int oq = blockIdx.x, b = blockIdx.y;
  const float* Bm = ws + WS_BMAT + (size_t)b * 128 * 128;

  for (int k = 0; k < 16; ++k) {
    int idx = tid + k * 256;
    int r = idx >> 5, f4 = idx & 31;
    *(float4*)&bs[r][f4 * 4] = *(const float4*)(Bm + r * 128 + f4 * 4);
  }
  for (int k = 0; k < 4; ++k) {
    int idx = tid + k * 256;
    int r = idx >> 5, f4 = idx & 31;
    *(float4*)&wos[r][f4 * 4] = *(const float4*)(w_out + (oq * 32 + r) * 128 + f4 * 4);
  }
  __syncthreads();

  const int ol = tid >> 3, cq = (tid & 7) * 16;
  float s[16];
  #pragma unroll
  for (int jj = 0; jj < 16; ++jj) s[jj] = 0.f;
  for (int eg = 0; eg < 128; ++eg) {
    float w = wos[ol][eg];
    #pragma unroll
    for (int jj = 0; jj < 16; ++jj) s[jj] = fmaf(w, bs[eg][cq + jj], s[jj]);
  }
  float* A = ws + WS_A + ((size_t)b * 128 + oq * 32 + ol) * 128;
  #pragma unroll
  for (int jj = 0; jj < 16; ++jj) A[cq + jj] = s[jj];
}

// ---------------------------------------------------------------------------
// K3: y[b] = A[b] @ x[b] + b_out  (bf16 MFMA, double-buffered xs)
// ---------------------------------------------------------------------------
__global__ __launch_bounds__(256, 4) void k3(const float* __restrict__ x,
                                             const float* __restrict__ bout,
                                             const float* __restrict__ ws,
                                             float* __restrict__ y) {
  __shared__ __attribute__((aligned(16))) unsigned short xs2[2][64][132];
  const int tid  = threadIdx.x;
  const int wave = tid >> 6;
  const int l15  = tid & 15;
  const int l4   = (tid >> 4) & 3;
  const int b    = blockIdx.y;
  const int n0   = blockIdx.x * 128;
  const float* xb = x + (size_t)b * ((size_t)C_ * N_);
  const float* A  = ws + WS_A + (size_t)b * 128 * 128;

  bf16x8 af[2][4];
  #pragma unroll
  for (int mi = 0; mi < 2; ++mi)
    #pragma unroll
    for (int ki = 0; ki < 4; ++ki) {
      const float* p = A + (size_t)(wave * 32 + mi * 16 + l15) * 128 + ki * 32 + l4 * 8;
      af[mi][ki] = make_frag(*(const float4*)p, *(const float4*)(p + 4));
    }
  float bias[2][4];
  #pragma unroll
  for (int mi = 0; mi < 2; ++mi)
    #pragma unroll
    for (int r = 0; r < 4; ++r)
      bias[mi][r] = bout[wave * 32 + mi * 16 + l4 * 4 + r];

  // stage subtile 0
  #pragma unroll
  for (int i = 0; i < 8; ++i) {
    int idx = tid + i * 256;
    int k = idx >> 4, n4 = idx & 15;
    float4 v = *(const float4*)(xb + (size_t)k * N_ + n0 + n4 * 4);
    unsigned int p01 = pkbf(v.x, v.y), p23 = pkbf(v.z, v.w);
    xs2[0][n4 * 4 + 0][k] = (unsigned short)p01;
    xs2[0][n4 * 4 + 1][k] = (unsigned short)(p01 >> 16);
    xs2[0][n4 * 4 + 2][k] = (unsigned short)p23;
    xs2[0][n4 * 4 + 3][k] = (unsigned short)(p23 >> 16);
  }
  __syncthreads();

  const f32x4 z4 = {0.f, 0.f, 0.f, 0.f};
  float* yb = y + (size_t)b * ((size_t)128 * N_);

  #pragma unroll
  for (int st = 0; st < 2; ++st) {
    const int nb = n0 + st * 64;
    f32x4 acc[2][4];
    #pragma unroll
    for (int mi = 0; mi < 2; ++mi)
      #pragma unroll
      for (int ni = 0; ni < 4; ++ni) acc[mi][ni] = z4;
    #pragma unroll
    for (int ki = 0; ki < 4; ++ki) {
      bf16x8 bfr[4];
      #pragma unroll
      for (int ni = 0; ni < 4; ++ni)
        bfr[ni] = lds_frag(&xs2[st][ni * 16 + l15][ki * 32 + l4 * 8]);
      #pragma unroll
      for (int mi = 0; mi < 2; ++mi)
        #pragma unroll
        for (int ni = 0; ni < 4; ++ni)
          acc[mi][ni] = __builtin_amdgcn_mfma_f32_16x16x32_bf16(
              af[mi][ki], bfr[ni], acc[mi][ni], 0, 0, 0);
    }

    if (st == 0) {
      // stage subtile 1 into other buffer (no barrier needed before writes)
      #pragma unroll
      for (int i = 0; i < 8; ++i) {
        int idx = tid + i * 256;
        int k = idx >> 4, n4 = idx & 15;
        float4 v = *(const float4*)(xb + (size_t)k * N_ + n0 + 64 + n4 * 4);
        unsigned int p01 = pkbf(v.x, v.y), p23 = pkbf(v.z, v.w);
        xs2[1][n4 * 4 + 0][k] = (unsigned short)p01;
        xs2[1][n4 * 4 + 1][k] = (unsigned short)(p01 >> 16);
        xs2[1][n4 * 4 + 2][k] = (unsigned short)p23;
        xs2[1][n4 * 4 + 3][k] = (unsigned short)(p23 >> 16);
      }
    }

    #pragma unroll
    for (int mi = 0; mi < 2; ++mi)
      #pragma unroll
      for (int ni = 0; ni < 4; ++ni)
        #pragma unroll
        for (int r = 0; r < 4; ++r)
          yb[(size_t)(wave * 32 + mi * 16 + l4 * 4 + r) * N_ + nb + ni * 16 + l15] =
              acc[mi][ni][r] + bias[mi][r];

    if (st == 0) __syncthreads();
  }
}

extern "C" void kernel_launch(void* const* d_in, const int* in_sizes, int n_in,
                              void* d_out, int out_size, void* d_ws, size_t ws_size,
                              hipStream_t stream) {
  const float* x     = (const float*)d_in[0];
  const float* w_qkv = (const float*)d_in[1];
  const float* w_out = (const float*)d_in[2];
  const float* b_out = (const float*)d_in[3];
  float* y  = (float*)d_out;
  float* ws = (float*)d_ws;

  const bool partial = ws_size >= (size_t)WS_END * sizeof(float);
  if (partial) {
    k1_kv_ctx<false><<<dim3(64, 8), 512, 0, stream>>>(x, w_qkv, ws);
    k1b<<<dim3(4, 4, 8), 256, 0, stream>>>(ws);
  } else {
    hipMemsetAsync(ws, 0, (1024 + 32768) * sizeof(float), stream);
    k1_kv_ctx<true><<<dim3(64, 8), 512, 0, stream>>>(x, w_qkv, ws);
  }
  k2a<<<dim3(4, 8), 256, 0, stream>>>(w_qkv, ws);
  k2b<<<dim3(4, 8), 256, 0, stream>>>(w_out, ws);
  k3<<<dim3(128, 8), 256, 0, stream>>>(x, b_out, ws, y);
}

// Round 4
// 79.893 us; speedup vs baseline: 6.2493x; 1.1177x over previous
//
#include <hip/hip_runtime.h>
#include <math.h>

#define C_ 128
#define N_ 16384

// ws layout (float offsets)
#define WS_Z    0                          // 8*128
#define WS_CTX  1024                       // 8*4*32*32
#define WS_BMAT 33792                      // 8*128*128
#define WS_A    164864                     // 8*128*128
#define WS_PCTX 295936                     // 1024 slots * 4096
#define WS_PZ   (WS_PCTX + 1024*4096)      // 512 blocks * 128
#define WS_END  (WS_PZ + 512*128)

typedef __attribute__((ext_vector_type(8))) short bf16x8;
typedef __attribute__((ext_vector_type(4))) float f32x4;
typedef __attribute__((ext_vector_type(4))) unsigned int u32x4;
typedef __attribute__((ext_vector_type(2))) unsigned int u32x2;

__device__ __forceinline__ unsigned int pkbf(float a, float b) {
  unsigned int r;
  asm("v_cvt_pk_bf16_f32 %0, %1, %2" : "=v"(r) : "v"(a), "v"(b));
  return r;
}

__device__ __forceinline__ bf16x8 make_frag(float4 u, float4 v) {
  u32x4 q = {pkbf(u.x, u.y), pkbf(u.z, u.w), pkbf(v.x, v.y), pkbf(v.z, v.w)};
  return *(bf16x8*)&q;
}

// 16B-aligned LDS fragment load -> ds_read_b128
__device__ __forceinline__ bf16x8 lds_frag16(const unsigned short* p) {
  u32x4 q = *(const u32x4*)p;
  return *(bf16x8*)&q;
}

__device__ __forceinline__ void load4(const float* p, float* o) {
  float4 v = *(const float4*)p;
  o[0] = v.x; o[1] = v.y; o[2] = v.z; o[3] = v.w;
}

// ---------------------------------------------------------------------------
// K1: per (b, 256-n chunk), 512 thr / 8 waves. Wave (h = w&3, t = w>>2):
//   t=0 -> K rows of head h, t=1 -> V rows. KV^T = x^T W^T via swapped MFMA;
//   ek = exp(K); ctx_h += ek_h @ v_h^T (n-half t per wave).
//   Single xs buffer + register prefetch (T14); 2 barriers/subtile.
// ---------------------------------------------------------------------------
template<bool ATOMIC>
__global__ __launch_bounds__(512, 2) void k1_kv_ctx(const float* __restrict__ x,
                                                    const float* __restrict__ wqkv,
                                                    float* __restrict__ ws) {
  __shared__ __attribute__((aligned(16))) unsigned short xs[64][136];     // 17.0 KB
  __shared__ __attribute__((aligned(16))) unsigned short ekv[2][128][72]; // 36.9 KB
  const int tid  = threadIdx.x;
  const int wave = tid >> 6;
  const int l15  = tid & 15;
  const int l4   = (tid >> 4) & 3;
  const int b    = blockIdx.y;
  const int j    = blockIdx.x;          // n-chunk 0..63
  const int h    = wave & 3;            // head
  const int t    = wave >> 2;           // 0 = K rows, 1 = V rows
  const int kvrow0 = h * 32 + t * 128;  // row within 256 KV rows
  const float* xb = x + (size_t)b * ((size_t)C_ * N_);

  // staging task: 4 c x 4 n per thread
  const int sn4 = tid & 15;             // n-quad
  const int scq = tid >> 4;             // c-quad 0..31

  // W fragments pinned in registers (32 VGPR)
  bf16x8 wf[2][4];
  #pragma unroll
  for (int mi = 0; mi < 2; ++mi)
    #pragma unroll
    for (int ki = 0; ki < 4; ++ki) {
      const float* p = wqkv + (size_t)(128 + kvrow0 + mi * 16 + l15) * C_ + ki * 32 + l4 * 8;
      wf[mi][ki] = make_frag(*(const float4*)p, *(const float4*)(p + 4));
    }

  // prologue: stage subtile 0
  {
    float va[4][4];
    #pragma unroll
    for (int r = 0; r < 4; ++r)
      load4(xb + (size_t)(scq * 4 + r) * N_ + j * 256 + sn4 * 4, va[r]);
    #pragma unroll
    for (int i = 0; i < 4; ++i) {
      u32x2 w = {pkbf(va[0][i], va[1][i]), pkbf(va[2][i], va[3][i])};
      *(u32x2*)&xs[sn4 * 4 + i][scq * 4] = w;
    }
  }
  __syncthreads();

  const f32x4 z4 = {0.f, 0.f, 0.f, 0.f};
  f32x4 ctxacc[2][2];
  #pragma unroll
  for (int i = 0; i < 2; ++i)
    #pragma unroll
    for (int jj = 0; jj < 2; ++jj) ctxacc[i][jj] = z4;
  float zacc[2] = {0.f, 0.f};

  for (int st = 0; st < 4; ++st) {
    // prefetch next subtile into registers (lands after ctx MFMA)
    float pf[4][4];
    if (st < 3) {
      const int nbn = j * 256 + (st + 1) * 64;
      #pragma unroll
      for (int r = 0; r < 4; ++r)
        load4(xb + (size_t)(scq * 4 + r) * N_ + nbn + sn4 * 4, pf[r]);
    }

    // KV^T: two ni-halves to cap register pressure
    #pragma unroll
    for (int half = 0; half < 2; ++half) {
      f32x4 acc[2][2];   // [ni2][mi]
      #pragma unroll
      for (int a = 0; a < 2; ++a)
        #pragma unroll
        for (int m = 0; m < 2; ++m) acc[a][m] = z4;
      #pragma unroll
      for (int ki = 0; ki < 4; ++ki) {
        bf16x8 bfr[2];
        #pragma unroll
        for (int ni2 = 0; ni2 < 2; ++ni2)
          bfr[ni2] = lds_frag16(&xs[half * 32 + ni2 * 16 + l15][ki * 32 + l4 * 8]);
        #pragma unroll
        for (int ni2 = 0; ni2 < 2; ++ni2)
          #pragma unroll
          for (int mi = 0; mi < 2; ++mi)
            acc[ni2][mi] = __builtin_amdgcn_mfma_f32_16x16x32_bf16(
                bfr[ni2], wf[mi][ki], acc[ni2][mi], 0, 0, 0);
      }
      // lane holds KV row m = kvrow0%128 + mi*16 + l15, 4 consecutive n
      #pragma unroll
      for (int ni2 = 0; ni2 < 2; ++ni2)
        #pragma unroll
        for (int mi = 0; mi < 2; ++mi) {
          float e0, e1, e2, e3;
          if (t == 0) {
            e0 = __expf(acc[ni2][mi][0]); e1 = __expf(acc[ni2][mi][1]);
            e2 = __expf(acc[ni2][mi][2]); e3 = __expf(acc[ni2][mi][3]);
            zacc[mi] += (e0 + e1) + (e2 + e3);
          } else {
            e0 = acc[ni2][mi][0]; e1 = acc[ni2][mi][1];
            e2 = acc[ni2][mi][2]; e3 = acc[ni2][mi][3];
          }
          u32x2 w = {pkbf(e0, e1), pkbf(e2, e3)};
          *(u32x2*)&ekv[t][h * 32 + mi * 16 + l15][(half * 2 + ni2) * 16 + l4 * 4] = w;
        }
    }
    __syncthreads();     // ekv ready

    // ctx_h[d][e] += ek_h[d][n] * v_h[e][n] over this wave's n-half t
    {
      bf16x8 af2[2], bv2[2];
      #pragma unroll
      for (int m2 = 0; m2 < 2; ++m2)
        af2[m2] = lds_frag16(&ekv[0][h * 32 + m2 * 16 + l15][t * 32 + l4 * 8]);
      #pragma unroll
      for (int n2 = 0; n2 < 2; ++n2)
        bv2[n2] = lds_frag16(&ekv[1][h * 32 + n2 * 16 + l15][t * 32 + l4 * 8]);
      #pragma unroll
      for (int m2 = 0; m2 < 2; ++m2)
        #pragma unroll
        for (int n2 = 0; n2 < 2; ++n2)
          ctxacc[m2][n2] = __builtin_amdgcn_mfma_f32_16x16x32_bf16(
              af2[m2], bv2[n2], ctxacc[m2][n2], 0, 0, 0);
    }

    // write prefetched subtile into xs (KV readers finished at barrier above)
    if (st < 3) {
      #pragma unroll
      for (int i = 0; i < 4; ++i) {
        u32x2 w = {pkbf(pf[0][i], pf[1][i]), pkbf(pf[2][i], pf[3][i])};
        *(u32x2*)&xs[sn4 * 4 + i][scq * 4] = w;
      }
    }
    __syncthreads();     // xs ready for next KV; ekv consumed
  }

  // epilogue
  if (!ATOMIC) {
    float* ps = ws + WS_PCTX + (size_t)((b * 64 + j) * 2 + t) * 4096 + h * 1024;
    #pragma unroll
    for (int m2 = 0; m2 < 2; ++m2)
      #pragma unroll
      for (int n2 = 0; n2 < 2; ++n2)
        #pragma unroll
        for (int r = 0; r < 4; ++r)
          ps[(m2 * 16 + l4 * 4 + r) * 32 + n2 * 16 + l15] = ctxacc[m2][n2][r];
  } else {
    float* ctx = ws + WS_CTX + (size_t)(b * 4 + h) * 1024;
    #pragma unroll
    for (int m2 = 0; m2 < 2; ++m2)
      #pragma unroll
      for (int n2 = 0; n2 < 2; ++n2)
        #pragma unroll
        for (int r = 0; r < 4; ++r)
          atomicAdd(&ctx[(m2 * 16 + l4 * 4 + r) * 32 + n2 * 16 + l15],
                    ctxacc[m2][n2][r]);
  }
  if (t == 0) {
    #pragma unroll
    for (int mi = 0; mi < 2; ++mi) {
      float z = zacc[mi];
      z += __shfl_xor(z, 16);
      z += __shfl_xor(z, 32);
      if ((tid & 48) == 0) {
        int row = h * 32 + mi * 16 + l15;
        if (!ATOMIC)
          ws[WS_PZ + (size_t)(b * 64 + j) * 128 + row] = z;
        else
          atomicAdd(&ws[WS_Z + b * 128 + row], z);
      }
    }
  }
}

// ---------------------------------------------------------------------------
// K1b: reduce partials -> WS_CTX, WS_Z
// ---------------------------------------------------------------------------
__global__ __launch_bounds__(256) void k1b(float* __restrict__ ws) {
  const int tid = threadIdx.x;
  const int eq = blockIdx.x;   // 0..3
  const int h  = blockIdx.y;   // 0..3
  const int b  = blockIdx.z;   // 0..7
  const int el = eq * 256 + tid;
  const float* p = ws + WS_PCTX + (size_t)(b * 128) * 4096 + h * 1024 + el;
  float s = 0.f;
  #pragma unroll 8
  for (int jj = 0; jj < 128; ++jj) s += p[(size_t)jj * 4096];
  ws[WS_CTX + (size_t)(b * 4 + h) * 1024 + el] = s;
  if (eq == 0 && tid < 32) {
    const float* pz = ws + WS_PZ + (size_t)(b * 64) * 128 + h * 32 + tid;
    float z = 0.f;
    #pragma unroll 8
    for (int jj = 0; jj < 64; ++jj) z += pz[(size_t)jj * 128];
    ws[WS_Z + b * 128 + h * 32 + tid] = z;
  }
}

// ---------------------------------------------------------------------------
// K2a: Bmat[b][h*32+e][c] = sum_d (ctx[b][h][d][e]/Z[b][h*32+d]) * w_qkv[h*32+d][c]
// ---------------------------------------------------------------------------
__global__ __launch_bounds__(256) void k2a(const float* __restrict__ w_qkv,
                                           float* __restrict__ ws) {
  __shared__ float cn[32][33];
  __shared__ float wqs[32][128];
  const int tid = threadIdx.x;
  const int h = blockIdx.x, b = blockIdx.y;
  const float* Z   = ws + WS_Z + b * 128 + h * 32;
  const float* ctx = ws + WS_CTX + ((b * 4 + h) * 32) * 32;

  for (int k = 0; k < 4; ++k) {
    int idx = tid + k * 256;
    int d = idx >> 5, e = idx & 31;
    cn[d][e] = ctx[d * 32 + e] / Z[d];
  }
  for (int k = 0; k < 4; ++k) {
    int idx = tid + k * 256;
    int d = idx >> 5, f4 = idx & 31;
    *(float4*)&wqs[d][f4 * 4] = *(const float4*)(w_qkv + (h * 32 + d) * 128 + f4 * 4);
  }
  __syncthreads();

  const int e = tid >> 3, cs = (tid & 7) * 16;
  float s[16];
  #pragma unroll
  for (int jj = 0; jj < 16; ++jj) s[jj] = 0.f;
  for (int d = 0; d < 32; ++d) {
    float v = cn[d][e];
    #pragma unroll
    for (int jj = 0; jj < 16; ++jj) s[jj] = fmaf(v, wqs[d][cs + jj], s[jj]);
  }
  float* Bm = ws + WS_BMAT + ((size_t)b * 128 + h * 32 + e) * 128;
  #pragma unroll
  for (int jj = 0; jj < 16; ++jj) Bm[cs + jj] = s[jj];
}

// ---------------------------------------------------------------------------
// K2b: A[b] = w_out @ Bmat[b]
// ---------------------------------------------------------------------------
__global__ __launch_bounds__(256) void k2b(const float* __restrict__ w_out,
                                           float* __restrict__ ws) {
  __shared__ float bs[128][128];
  __shared__ float wos[32][128];
  const int tid = threadIdx.x;
  const int oq = blockIdx.x, b = blockIdx.y;
  const float* Bm = ws + WS_BMAT + (size_t)b * 128 * 128;

  for (int k = 0; k < 16; ++k) {
    int idx = tid + k * 256;
    int r = idx >> 5, f4 = idx & 31;
    *(float4*)&bs[r][f4 * 4] = *(const float4*)(Bm + r * 128 + f4 * 4);
  }
  for (int k = 0; k < 4; ++k) {
    int idx = tid + k * 256;
    int r = idx >> 5, f4 = idx & 31;
    *(float4*)&wos[r][f4 * 4] = *(const float4*)(w_out + (oq * 32 + r) * 128 + f4 * 4);
  }
  __syncthreads();

  const int ol = tid >> 3, cq = (tid & 7) * 16;
  float s[16];
  #pragma unroll
  for (int jj = 0; jj < 16; ++jj) s[jj] = 0.f;
  for (int eg = 0; eg < 128; ++eg) {
    float w = wos[ol][eg];
    #pragma unroll
    for (int jj = 0; jj < 16; ++jj) s[jj] = fmaf(w, bs[eg][cq + jj], s[jj]);
  }
  float* A = ws + WS_A + ((size_t)b * 128 + oq * 32 + ol) * 128;
  #pragma unroll
  for (int jj = 0; jj < 16; ++jj) A[cq + jj] = s[jj];
}

// ---------------------------------------------------------------------------
// K3: y[b] = A[b] @ x[b] + b_out  (swapped MFMA -> dwordx4 stores)
// ---------------------------------------------------------------------------
__global__ __launch_bounds__(256, 4) void k3(const float* __restrict__ x,
                                             const float* __restrict__ bout,
                                             const float* __restrict__ ws,
                                             float* __restrict__ y) {
  __shared__ __attribute__((aligned(16))) unsigned short xs2[2][64][136];
  const int tid  = threadIdx.x;
  const int wave = tid >> 6;
  const int l15  = tid & 15;
  const int l4   = (tid >> 4) & 3;
  const int b    = blockIdx.y;
  const int n0   = blockIdx.x * 128;
  const float* xb = x + (size_t)b * ((size_t)C_ * N_);
  const float* A  = ws + WS_A + (size_t)b * 128 * 128;

  bf16x8 af[2][4];
  #pragma unroll
  for (int mi = 0; mi < 2; ++mi)
    #pragma unroll
    for (int ki = 0; ki < 4; ++ki) {
      const float* p = A + (size_t)(wave * 32 + mi * 16 + l15) * 128 + ki * 32 + l4 * 8;
      af[mi][ki] = make_frag(*(const float4*)p, *(const float4*)(p + 4));
    }
  float bias[2];
  #pragma unroll
  for (int mi = 0; mi < 2; ++mi) bias[mi] = bout[wave * 32 + mi * 16 + l15];

  // stage subtile 0 (2 tasks of 4c x 4n per thread)
  #pragma unroll
  for (int it = 0; it < 2; ++it) {
    int idx = tid + it * 256;
    int n4 = idx & 15, cq = idx >> 4;
    float va[4][4];
    #pragma unroll
    for (int r = 0; r < 4; ++r)
      load4(xb + (size_t)(cq * 4 + r) * N_ + n0 + n4 * 4, va[r]);
    #pragma unroll
    for (int i = 0; i < 4; ++i) {
      u32x2 w = {pkbf(va[0][i], va[1][i]), pkbf(va[2][i], va[3][i])};
      *(u32x2*)&xs2[0][n4 * 4 + i][cq * 4] = w;
    }
  }
  __syncthreads();

  const f32x4 z4 = {0.f, 0.f, 0.f, 0.f};
  float* yb = y + (size_t)b * ((size_t)128 * N_);

  #pragma unroll
  for (int st = 0; st < 2; ++st) {
    const int nb = n0 + st * 64;
    f32x4 acc[4][2];   // [ni][mi]
    #pragma unroll
    for (int ni = 0; ni < 4; ++ni)
      #pragma unroll
      for (int mi = 0; mi < 2; ++mi) acc[ni][mi] = z4;
    #pragma unroll
    for (int ki = 0; ki < 4; ++ki) {
      bf16x8 bfr[4];
      #pragma unroll
      for (int ni = 0; ni < 4; ++ni)
        bfr[ni] = lds_frag16(&xs2[st][ni * 16 + l15][ki * 32 + l4 * 8]);
      #pragma unroll
      for (int ni = 0; ni < 4; ++ni)
        #pragma unroll
        for (int mi = 0; mi < 2; ++mi)
          acc[ni][mi] = __builtin_amdgcn_mfma_f32_16x16x32_bf16(
              bfr[ni], af[mi][ki], acc[ni][mi], 0, 0, 0);
    }

    if (st == 0) {
      // stage subtile 1 (other buffer) — overlaps with MFMA latency
      #pragma unroll
      for (int it = 0; it < 2; ++it) {
        int idx = tid + it * 256;
        int n4 = idx & 15, cq = idx >> 4;
        float va[4][4];
        #pragma unroll
        for (int r = 0; r < 4; ++r)
          load4(xb + (size_t)(cq * 4 + r) * N_ + n0 + 64 + n4 * 4, va[r]);
        #pragma unroll
        for (int i = 0; i < 4; ++i) {
          u32x2 w = {pkbf(va[0][i], va[1][i]), pkbf(va[2][i], va[3][i])};
          *(u32x2*)&xs2[1][n4 * 4 + i][cq * 4] = w;
        }
      }
    }

    // lane holds y row m = wave*32 + mi*16 + l15, 4 consecutive n
    #pragma unroll
    for (int ni = 0; ni < 4; ++ni)
      #pragma unroll
      for (int mi = 0; mi < 2; ++mi) {
        float4 o;
        o.x = acc[ni][mi][0] + bias[mi];
        o.y = acc[ni][mi][1] + bias[mi];
        o.z = acc[ni][mi][2] + bias[mi];
        o.w = acc[ni][mi][3] + bias[mi];
        *(float4*)(yb + (size_t)(wave * 32 + mi * 16 + l15) * N_ + nb + ni * 16 + l4 * 4) = o;
      }

    if (st == 0) __syncthreads();
  }
}

extern "C" void kernel_launch(void* const* d_in, const int* in_sizes, int n_in,
                              void* d_out, int out_size, void* d_ws, size_t ws_size,
                              hipStream_t stream) {
  const float* x     = (const float*)d_in[0];
  const float* w_qkv = (const float*)d_in[1];
  const float* w_out = (const float*)d_in[2];
  const float* b_out = (const float*)d_in[3];
  float* y  = (float*)d_out;
  float* ws = (float*)d_ws;

  const bool partial = ws_size >= (size_t)WS_END * sizeof(float);
  if (partial) {
    k1_kv_ctx<false><<<dim3(64, 8), 512, 0, stream>>>(x, w_qkv, ws);
    k1b<<<dim3(4, 4, 8), 256, 0, stream>>>(ws);
  } else {
    hipMemsetAsync(ws, 0, (1024 + 32768) * sizeof(float), stream);
    k1_kv_ctx<true><<<dim3(64, 8), 512, 0, stream>>>(x, w_qkv, ws);
  }
  k2a<<<dim3(4, 8), 256, 0, stream>>>(w_qkv, ws);
  k2b<<<dim3(4, 8), 256, 0, stream>>>(w_out, ws);
  k3<<<dim3(128, 8), 256, 0, stream>>>(x, b_out, ws, y);
}